// Round 1
// 265.516 us; speedup vs baseline: 1.0447x; 1.0447x over previous
//
#include <hip/hip_runtime.h>
#include <hip/hip_bf16.h>
#include <math.h>

#define N_NODES 50000
#define FDIM 64
#define BETA 0.5f
#define NEG_SLOPE 0.2f

typedef __attribute__((ext_vector_type(8))) short bf16x8;
typedef __attribute__((ext_vector_type(4))) float f32x4;

__device__ __forceinline__ unsigned short f2bf(float f) {
    unsigned u = __float_as_uint(f);
    unsigned r = (u + 0x7FFFu + ((u >> 16) & 1u)) >> 16;
    return (unsigned short)r;
}
__device__ __forceinline__ float bf2f(unsigned short s) {
    return __uint_as_float((unsigned)s << 16);
}

// ---------------------------------------------------------------------------
// Single-pass bucketed scatter: packed (src | dlow<<16) into PADDED per-bucket
// regions (bucket = dst>>8, region stride CAP). No global hist pass needed --
// the compact exclusive scan is deferred to bucket_sort over final counts.
// int64/int32 self-detection per block (odd dwords of int64 are zero, N<2^31).
#define CHUNK 2048
__global__ __launch_bounds__(256) void scatter_pairs(
    const unsigned int* __restrict__ eiu, const int* __restrict__ ei32,
    const long long* __restrict__ ei64, int* __restrict__ gCursor,
    unsigned int* __restrict__ pairs, int E, int CAP) {
    __shared__ int det;
    __shared__ int hist[256], base[256], cur[256];
    int t = threadIdx.x;
    if (t == 0) det = 0;
    hist[t] = 0; cur[t] = 0;
    __syncthreads();
    int beg = blockIdx.x * CHUNK;
    int end = min(E, beg + CHUNK);
    {
        int idx = beg + t;
        if (idx < E && eiu[2 * idx + 1] != 0u) atomicOr(&det, 1);
    }
    __syncthreads();
    bool is32 = det != 0;
    for (int i = beg + t; i < end; i += 256) {
        int d = is32 ? ei32[E + i] : (int)ei64[E + i];
        atomicAdd(&hist[d >> 8], 1);
    }
    __syncthreads();
    if (hist[t] > 0) base[t] = t * CAP + atomicAdd(&gCursor[t], hist[t]);
    __syncthreads();
    for (int i = beg + t; i < end; i += 256) {
        int s, d;
        if (is32) { s = ei32[i]; d = ei32[E + i]; }
        else      { s = (int)ei64[i]; d = (int)ei64[E + i]; }
        int b = d >> 8;
        int pos = base[b] + atomicAdd(&cur[b], 1);
        pairs[pos] = (unsigned int)s | ((unsigned int)(d & 255) << 16);
    }
}

// One block (1024 thr, 16 waves) per bucket: counting sort by full dst.
// Global compact offsets come from an exclusive scan over final gCursor counts.
__global__ __launch_bounds__(1024) void bucket_sort(
    const unsigned int* __restrict__ pairs, const int* __restrict__ gCursor,
    int* __restrict__ offsets, int* __restrict__ srcs, int N, int E, int CAP) {
    __shared__ int scb[256], cnt[256], sc[256], cur[256];
    int b = blockIdx.x, t = threadIdx.x;
    if (t < 256) scb[t] = gCursor[t];
    __syncthreads();
    for (int off = 1; off < 256; off <<= 1) {
        int v = (t < 256 && t >= off) ? scb[t - off] : 0;
        __syncthreads();
        if (t < 256) scb[t] += v;
        __syncthreads();
    }
    int cntb = gCursor[b];
    int beg = scb[b] - cntb;       // global compact begin of this bucket
    int pbase = b * CAP;           // padded source region
    if (b == 0 && t == 0) offsets[N] = E;
    if (t < 256) cnt[t] = 0;
    __syncthreads();
    for (int i = t; i < cntb; i += 1024) atomicAdd(&cnt[(pairs[pbase + i] >> 16) & 255u], 1);
    __syncthreads();
    if (t < 256) sc[t] = cnt[t];
    __syncthreads();
    for (int off = 1; off < 256; off <<= 1) {
        int v = (t < 256 && t >= off) ? sc[t - off] : 0;
        __syncthreads();
        if (t < 256) sc[t] += v;
        __syncthreads();
    }
    if (t < 256) {
        int excl = sc[t] - cnt[t];
        int node = (b << 8) + t;
        if (node < N) offsets[node] = beg + excl;
        cur[t] = beg + excl;
    }
    __syncthreads();
    for (int i = t; i < cntb; i += 1024) {
        unsigned int p = pairs[pbase + i];
        int pos = atomicAdd(&cur[(p >> 16) & 255u], 1);
        srcs[pos] = (int)(p & 0xFFFFu);
    }
}

// ---------------------------------------------------------------------------
// Prep: transpose W and fc_w into bf16 hi/lo, WT[f*64+k] = split(W[k*64+f]).
__global__ __launch_bounds__(256) void prep_weights(
    const float* __restrict__ W, const float* __restrict__ fcw,
    unsigned short* __restrict__ WTh, unsigned short* __restrict__ WTl,
    unsigned short* __restrict__ FTh, unsigned short* __restrict__ FTl) {
    for (int idx = blockIdx.x * 256 + threadIdx.x; idx < 4096; idx += gridDim.x * 256) {
        int k = idx >> 6, f = idx & 63;
        float w = W[idx];
        unsigned short hi = f2bf(w);
        WTh[f * 64 + k] = hi;
        WTl[f * 64 + k] = f2bf(w - bf2f(hi));
        float w2 = fcw[idx];
        unsigned short hi2 = f2bf(w2);
        FTh[f * 64 + k] = hi2;
        FTl[f * 64 + k] = f2bf(w2 - bf2f(hi2));
    }
}

// ---------------------------------------------------------------------------
// Split-bf16 MFMA transform: h = x@W (fp32-accurate via xh*Wh + xh*Wl + xl*Wh).
// hb written CONTIGUOUS: hb[node*64 + f].
__global__ __launch_bounds__(256, 4) void transform_mfma(
    const float* __restrict__ x,
    const unsigned short* __restrict__ WTh, const unsigned short* __restrict__ WTl,
    const float* __restrict__ a_src, const float* __restrict__ a_dst,  // nullable
    const float* __restrict__ bias,                                    // nullable
    unsigned short* __restrict__ hb,  // bf16 out (layers), nullable
    float* __restrict__ fout,         // fp32 out (FC), nullable
    float* __restrict__ as_, float* __restrict__ ad_, int N) {
    __shared__ __align__(16) unsigned short WThs[64 * 72];
    __shared__ __align__(16) unsigned short WTls[64 * 72];
    int tid = threadIdx.x;
    {
        int row = tid >> 2;            // 0..63
        int ch = (tid & 3) * 16;       // shorts
        uint4 h0 = ((const uint4*)(WTh + row * 64 + ch))[0];
        uint4 h1 = ((const uint4*)(WTh + row * 64 + ch))[1];
        uint4 l0 = ((const uint4*)(WTl + row * 64 + ch))[0];
        uint4 l1 = ((const uint4*)(WTl + row * 64 + ch))[1];
        *((uint4*)(WThs + row * 72 + ch)) = h0;
        *((uint4*)(WThs + row * 72 + ch + 8)) = h1;
        *((uint4*)(WTls + row * 72 + ch)) = l0;
        *((uint4*)(WTls + row * 72 + ch + 8)) = l1;
    }

    int wid = tid >> 6;
    int lane = tid & 63;
    int col = lane & 15;
    int quad = lane >> 4;
    int mbase = blockIdx.x * 64 + wid * 16;

    bf16x8 Ah[2], Al[2];
    int arow = mbase + col;
    const float* xr = x + (size_t)(arow < N ? arow : 0) * FDIM + quad * 8;
#pragma unroll
    for (int ks = 0; ks < 2; ks++) {
        float4 xa = *(const float4*)(xr + ks * 32);
        float4 xb = *(const float4*)(xr + ks * 32 + 4);
        float xv[8] = {xa.x, xa.y, xa.z, xa.w, xb.x, xb.y, xb.z, xb.w};
#pragma unroll
        for (int e = 0; e < 8; e++) {
            unsigned short hi = f2bf(xv[e]);
            Ah[ks][e] = (short)hi;
            Al[ks][e] = (short)f2bf(xv[e] - bf2f(hi));
        }
    }
    __syncthreads();

    f32x4 acc[4];
#pragma unroll
    for (int ft = 0; ft < 4; ft++) acc[ft] = (f32x4){0.f, 0.f, 0.f, 0.f};

#pragma unroll
    for (int ft = 0; ft < 4; ft++) {
        int f = ft * 16 + col;
#pragma unroll
        for (int ks = 0; ks < 2; ks++) {
            int off = f * 72 + ks * 32 + quad * 8;
            bf16x8 Bh = *(const bf16x8*)(WThs + off);
            bf16x8 Bl = *(const bf16x8*)(WTls + off);
            acc[ft] = __builtin_amdgcn_mfma_f32_16x16x32_bf16(Ah[ks], Bh, acc[ft], 0, 0, 0);
            acc[ft] = __builtin_amdgcn_mfma_f32_16x16x32_bf16(Ah[ks], Bl, acc[ft], 0, 0, 0);
            acc[ft] = __builtin_amdgcn_mfma_f32_16x16x32_bf16(Al[ks], Bh, acc[ft], 0, 0, 0);
        }
    }

    if (fout) {
#pragma unroll
        for (int ft = 0; ft < 4; ft++) {
            int f = ft * 16 + col;
            float bv = bias ? bias[f] : 0.f;
#pragma unroll
            for (int r = 0; r < 4; r++) {
                int node = mbase + quad * 4 + r;
                if (node < N) fout[(size_t)node * FDIM + f] = acc[ft][r] + bv;
            }
        }
    }
    if (hb) {
#pragma unroll
        for (int ft = 0; ft < 4; ft++) {
            int f = ft * 16 + col;
#pragma unroll
            for (int r = 0; r < 4; r++) {
                int node = mbase + quad * 4 + r;
                if (node < N) hb[(size_t)node * FDIM + f] = f2bf(acc[ft][r]);
            }
        }
    }
    if (as_) {
        float asv[4], adv[4];
#pragma unroll
        for (int ft = 0; ft < 4; ft++) {
            asv[ft] = a_src[ft * 16 + col];
            adv[ft] = a_dst[ft * 16 + col];
        }
#pragma unroll
        for (int r = 0; r < 4; r++) {
            float pa = 0.f, pd = 0.f;
#pragma unroll
            for (int ft = 0; ft < 4; ft++) {
                pa = fmaf(acc[ft][r], asv[ft], pa);
                pd = fmaf(acc[ft][r], adv[ft], pd);
            }
#pragma unroll
            for (int off = 1; off <= 8; off <<= 1) {
                pa += __shfl_xor(pa, off, 64);
                pd += __shfl_xor(pd, off, 64);
            }
            int node = mbase + quad * 4 + r;
            if (col == 0 && node < N) { as_[node] = pa; ad_[node] = pd; }
        }
    }
}

// ---------------------------------------------------------------------------
// One wave per dst node, single-pass fused softmax. LDS-FREE: the 8 feature
// lanes of each edge slot redundantly load srcs[i] (same address -> 1 merged
// request) and as_[s] (same address per slot group), and recompute exp
// (~6 VALU). This cuts the per-edge-group dependent chain from 4 serialized
// memory latencies (srcs -> as_ -> LDS write -> LDS read -> h) to 2
// (srcs -> h, with as_+exp hidden under the h load), and raises outstanding
// vmem from 4 to 12 per wave (R11 post-mortem: gather is MLP-bound).
__global__ __launch_bounds__(256) void gat_gather(
    const unsigned short* __restrict__ hb,
    const float* __restrict__ as_, const float* __restrict__ ad_,
    const int* __restrict__ offsets, const int* __restrict__ srcs,
    const float* __restrict__ bvec, const float* __restrict__ x0,
    float* __restrict__ xout, int N) {
    int wid = (blockIdx.x * blockDim.x + threadIdx.x) >> 6;
    if (wid >= N) return;
    int lane = threadIdx.x & 63;
    int q = lane & 7;        // feature octet 0..7 (8 bf16 each)
    int eslot = lane >> 3;   // edge slot 0..7
    int beg = offsets[wid], end = offsets[wid + 1];
    float adv = ad_[wid];

    float acc[8];
#pragma unroll
    for (int k = 0; k < 8; k++) acc[k] = 0.f;
    float denom = 0.f;
    const unsigned short* hq = hb + (q << 3);   // + q*8 shorts (16B)

#define FMA8(EX, HV)                                                         \
    {                                                                        \
        acc[0] = fmaf(EX, __uint_as_float((HV).x << 16), acc[0]);            \
        acc[1] = fmaf(EX, __uint_as_float((HV).x & 0xFFFF0000u), acc[1]);    \
        acc[2] = fmaf(EX, __uint_as_float((HV).y << 16), acc[2]);            \
        acc[3] = fmaf(EX, __uint_as_float((HV).y & 0xFFFF0000u), acc[3]);    \
        acc[4] = fmaf(EX, __uint_as_float((HV).z << 16), acc[4]);            \
        acc[5] = fmaf(EX, __uint_as_float((HV).z & 0xFFFF0000u), acc[5]);    \
        acc[6] = fmaf(EX, __uint_as_float((HV).w << 16), acc[6]);            \
        acc[7] = fmaf(EX, __uint_as_float((HV).w & 0xFFFF0000u), acc[7]);    \
    }
#define LRELU_EXP(E_) __expf((E_) > 0.f ? (E_) : NEG_SLOPE * (E_))

    int i = beg + eslot;
    // 4-deep pipeline: 4 src loads issue back-to-back, then 4 h-row loads +
    // 4 as_ gathers (all independent), then exp + 32 FMAs.
    for (; i + 24 < end; i += 32) {
        int s0 = srcs[i];
        int s1 = srcs[i + 8];
        int s2 = srcs[i + 16];
        int s3 = srcs[i + 24];
        uint4 hv0 = *(const uint4*)(hq + ((size_t)s0 << 6));
        uint4 hv1 = *(const uint4*)(hq + ((size_t)s1 << 6));
        uint4 hv2 = *(const uint4*)(hq + ((size_t)s2 << 6));
        uint4 hv3 = *(const uint4*)(hq + ((size_t)s3 << 6));
        float e0 = as_[s0] + adv;
        float e1 = as_[s1] + adv;
        float e2 = as_[s2] + adv;
        float e3 = as_[s3] + adv;
        float ex0 = LRELU_EXP(e0);
        float ex1 = LRELU_EXP(e1);
        float ex2 = LRELU_EXP(e2);
        float ex3 = LRELU_EXP(e3);
        denom += (ex0 + ex1) + (ex2 + ex3);
        FMA8(ex0, hv0);
        FMA8(ex1, hv1);
        FMA8(ex2, hv2);
        FMA8(ex3, hv3);
    }
    for (; i < end; i += 8) {
        int s0 = srcs[i];
        uint4 hv0 = *(const uint4*)(hq + ((size_t)s0 << 6));
        float e0 = as_[s0] + adv;
        float ex0 = LRELU_EXP(e0);
        denom += ex0;
        FMA8(ex0, hv0);
    }
#undef FMA8
#undef LRELU_EXP

    // reduce across the 8 edge slots (each edge counted once per slot group)
#pragma unroll
    for (int off = 8; off <= 32; off <<= 1) {
        denom += __shfl_xor(denom, off, 64);
#pragma unroll
        for (int k = 0; k < 8; k++) acc[k] += __shfl_xor(acc[k], off, 64);
    }
    if (lane < 8) {   // lane == q, eslot == 0: owns features q*8 .. q*8+7
        float inv = denom > 0.f ? 1.f / denom : 0.f;
        int fb = lane * 8;
        f32x4 b0 = *(const f32x4*)(bvec + fb);
        f32x4 b1 = *(const f32x4*)(bvec + fb + 4);
        f32x4 x0a = *(const f32x4*)(x0 + (size_t)wid * FDIM + fb);
        f32x4 x0b = *(const f32x4*)(x0 + (size_t)wid * FDIM + fb + 4);
        f32x4 o0, o1;
        o0.x = BETA * (acc[0] * inv + b0.x) + (1.f - BETA) * x0a.x;
        o0.y = BETA * (acc[1] * inv + b0.y) + (1.f - BETA) * x0a.y;
        o0.z = BETA * (acc[2] * inv + b0.z) + (1.f - BETA) * x0a.z;
        o0.w = BETA * (acc[3] * inv + b0.w) + (1.f - BETA) * x0a.w;
        o1.x = BETA * (acc[4] * inv + b1.x) + (1.f - BETA) * x0b.x;
        o1.y = BETA * (acc[5] * inv + b1.y) + (1.f - BETA) * x0b.y;
        o1.z = BETA * (acc[6] * inv + b1.z) + (1.f - BETA) * x0b.z;
        o1.w = BETA * (acc[7] * inv + b1.w) + (1.f - BETA) * x0b.w;
        *(f32x4*)(xout + (size_t)wid * FDIM + fb) = o0;
        *(f32x4*)(xout + (size_t)wid * FDIM + fb + 4) = o1;
    }
}

// ---------------------------------------------------------------------------
extern "C" void kernel_launch(void* const* d_in, const int* in_sizes, int n_in,
                              void* d_out, int out_size, void* d_ws, size_t ws_size,
                              hipStream_t stream) {
    const int N = N_NODES;
    const int E = in_sizes[1] / 2;
    const int NB = (N + 255) >> 8;   // 196 buckets
    // padded per-bucket capacity: 2x the uniform mean, rounded up
    const int CAP = (((E / N) * 256) * 2 + 1023) & ~1023;

    const float* x     = (const float*)d_in[0];
    const void*  ei    = d_in[1];
    const float* W     = (const float*)d_in[2];
    const float* a_src = (const float*)d_in[3];
    const float* a_dst = (const float*)d_in[4];
    const float* bvec  = (const float*)d_in[5];
    const float* fc_w  = (const float*)d_in[6];
    const float* fc_b  = (const float*)d_in[7];

    float* out = (float*)d_out;                 // [N, F]
    float* x3  = out + (size_t)N * FDIM;        // [N, F] (second output = h)

    char* p = (char*)d_ws;
    auto alloc = [&](size_t bytes) -> void* {
        void* r = (void*)p;
        p += (bytes + 255) & ~(size_t)255;
        return r;
    };
    int*            gCursor  = (int*)alloc(256 * 4);
    unsigned int*   pairs    = (unsigned int*)alloc((size_t)256 * CAP * 4);
    int*            srcs     = (int*)alloc((size_t)E * 4);
    int*            offsets  = (int*)alloc((size_t)(N + 1) * 4);
    float*          as_      = (float*)alloc((size_t)N * 4);
    float*          ad_      = (float*)alloc((size_t)N * 4);
    unsigned short* hbuf     = (unsigned short*)alloc((size_t)N * FDIM * 2);
    float*          xbuf     = (float*)alloc((size_t)N * FDIM * 4);
    unsigned short* WTh      = (unsigned short*)alloc(4096 * 2);
    unsigned short* WTl      = (unsigned short*)alloc(4096 * 2);
    unsigned short* FTh      = (unsigned short*)alloc(4096 * 2);
    unsigned short* FTl      = (unsigned short*)alloc(4096 * 2);

    hipMemsetAsync(gCursor, 0, 256 * 4, stream);

    prep_weights<<<16, 256, 0, stream>>>(W, fc_w, WTh, WTl, FTh, FTl);

    scatter_pairs<<<(E + CHUNK - 1) / CHUNK, 256, 0, stream>>>(
        (const unsigned int*)ei, (const int*)ei, (const long long*)ei,
        gCursor, pairs, E, CAP);
    bucket_sort<<<NB, 1024, 0, stream>>>(pairs, gCursor, offsets, srcs, N, E, CAP);

    int tgrid = (N + 63) / 64;
    int ggrid = (N * 64 + 255) / 256;

    // layer 1
    transform_mfma<<<tgrid, 256, 0, stream>>>(x, WTh, WTl, a_src, a_dst, nullptr,
                                              hbuf, nullptr, as_, ad_, N);
    gat_gather<<<ggrid, 256, 0, stream>>>(hbuf, as_, ad_, offsets, srcs, bvec, x, xbuf, N);
    // layer 2
    transform_mfma<<<tgrid, 256, 0, stream>>>(xbuf, WTh, WTl, a_src, a_dst, nullptr,
                                              hbuf, nullptr, as_, ad_, N);
    gat_gather<<<ggrid, 256, 0, stream>>>(hbuf, as_, ad_, offsets, srcs, bvec, x, xbuf, N);
    // layer 3
    transform_mfma<<<tgrid, 256, 0, stream>>>(xbuf, WTh, WTl, a_src, a_dst, nullptr,
                                              hbuf, nullptr, as_, ad_, N);
    gat_gather<<<ggrid, 256, 0, stream>>>(hbuf, as_, ad_, offsets, srcs, bvec, x, x3, N);
    // final fc: out = x3 @ fc_w + fc_b
    transform_mfma<<<tgrid, 256, 0, stream>>>(x3, FTh, FTl, nullptr, nullptr, fc_b,
                                              nullptr, out, nullptr, nullptr, N);
}